// Round 1
// baseline (339.710 us; speedup 1.0000x reference)
//
#include <hip/hip_runtime.h>
#include <math.h>

#define HW 36864
#define CC 192

typedef __attribute__((ext_vector_type(4))) float f32x4;
typedef __attribute__((ext_vector_type(8))) short bf16x8;

__device__ __forceinline__ float bf2f(unsigned short u) {
    return __uint_as_float(((unsigned int)u) << 16);
}
__device__ __forceinline__ unsigned short f2bf(float f) {
    unsigned int u = __float_as_uint(f);
    unsigned int r = (u + 0x7fffu + ((u >> 16) & 1u)) >> 16;
    return (unsigned short)r;
}

// ---------------------------------------------------------------------------
// GEMM: Out[b][m][n] = sum_k A[b][m][k] * X[b][k][n]
// A: bf16 [M][192] (k contiguous), X: f32 or bf16 [192][HW] (n contiguous)
// BM=64, BN=128, BK=32. 256 threads (4 waves), wave owns 64x32 of C.
// ---------------------------------------------------------------------------
template<bool XF32, bool OUTBF>
__global__ __launch_bounds__(256) void gemm_bf16(
    const unsigned short* __restrict__ A,
    const void* __restrict__ Xv,
    void* __restrict__ Outv,
    long aBatchStride, long xBatchStride, long oBatchStride)
{
    const int m0 = blockIdx.x * 64;
    const int n0 = blockIdx.y * 128;
    const int b  = blockIdx.z;
    const int tid = threadIdx.x;
    const int lane = tid & 63;
    const int wave = tid >> 6;

    __shared__ __attribute__((aligned(16))) unsigned short As[4 * 64 * 8]; // [q][m][8]
    __shared__ __attribute__((aligned(16))) unsigned short Xs[128 * 34];   // [n][k], stride 34

    const unsigned short* Ab = A + (long)b * aBatchStride;

    f32x4 acc[4][2];
#pragma unroll
    for (int f = 0; f < 4; ++f)
#pragma unroll
        for (int g = 0; g < 2; ++g)
            acc[f][g] = (f32x4){0.f, 0.f, 0.f, 0.f};

    const int am = tid >> 2, aq = tid & 3;   // A staging: m row, 16B chunk
    const int kp = tid & 15, nc = tid >> 4;  // X staging: k-pair, n-chunk of 8
    const int qk = lane >> 4, ml = lane & 15;

    for (int k0 = 0; k0 < 192; k0 += 32) {
        // stage A tile 64x32 -> fragment-ready layout
        {
            const unsigned short* src = Ab + (long)(m0 + am) * 192 + k0 + aq * 8;
            *(int4*)&As[(aq * 64 + am) * 8] = *(const int4*)src;
        }
        // stage X tile 32x128 transposed into Xs[n][k]
        {
            const int k = k0 + 2 * kp;
            const int n = n0 + nc * 8;
            unsigned int pk[8];
            if (XF32) {
                const float* xp = (const float*)Xv + (long)b * xBatchStride + (long)k * HW + n;
                float4 a0 = *(const float4*)(xp);
                float4 a1 = *(const float4*)(xp + 4);
                float4 b0 = *(const float4*)(xp + HW);
                float4 b1 = *(const float4*)(xp + HW + 4);
                float lo[8] = {a0.x, a0.y, a0.z, a0.w, a1.x, a1.y, a1.z, a1.w};
                float hi[8] = {b0.x, b0.y, b0.z, b0.w, b1.x, b1.y, b1.z, b1.w};
#pragma unroll
                for (int j = 0; j < 8; ++j)
                    pk[j] = (unsigned int)f2bf(lo[j]) | ((unsigned int)f2bf(hi[j]) << 16);
            } else {
                const unsigned short* xp = (const unsigned short*)Xv + (long)b * xBatchStride + (long)k * HW + n;
                int4 r0 = *(const int4*)(xp);
                int4 r1 = *(const int4*)(xp + HW);
                const unsigned short* u0 = (const unsigned short*)&r0;
                const unsigned short* u1 = (const unsigned short*)&r1;
#pragma unroll
                for (int j = 0; j < 8; ++j)
                    pk[j] = (unsigned int)u0[j] | ((unsigned int)u1[j] << 16);
            }
#pragma unroll
            for (int j = 0; j < 8; ++j)
                *(unsigned int*)&Xs[(nc * 8 + j) * 34 + 2 * kp] = pk[j];
        }
        __syncthreads();

        bf16x8 afr[4];
#pragma unroll
        for (int f = 0; f < 4; ++f)
            afr[f] = *(const bf16x8*)&As[(qk * 64 + f * 16 + ml) * 8];
        bf16x8 bfr[2];
#pragma unroll
        for (int g = 0; g < 2; ++g) {
            const unsigned short* p = &Xs[(wave * 32 + g * 16 + ml) * 34 + qk * 8];
            union { bf16x8 v; unsigned int u[4]; } tmp;
            tmp.u[0] = *(const unsigned int*)(p + 0);
            tmp.u[1] = *(const unsigned int*)(p + 2);
            tmp.u[2] = *(const unsigned int*)(p + 4);
            tmp.u[3] = *(const unsigned int*)(p + 6);
            bfr[g] = tmp.v;
        }
#pragma unroll
        for (int f = 0; f < 4; ++f)
#pragma unroll
            for (int g = 0; g < 2; ++g)
                acc[f][g] = __builtin_amdgcn_mfma_f32_16x16x32_bf16(afr[f], bfr[g], acc[f][g], 0, 0, 0);
        __syncthreads();
    }

    const int rq = lane >> 4, cl = lane & 15;
    if (OUTBF) {
        unsigned short* Out = (unsigned short*)Outv + (long)b * oBatchStride;
#pragma unroll
        for (int f = 0; f < 4; ++f)
#pragma unroll
            for (int g = 0; g < 2; ++g) {
                const int gm = m0 + f * 16 + rq * 4;
                const int gn = n0 + wave * 32 + g * 16 + cl;
#pragma unroll
                for (int i = 0; i < 4; ++i)
                    Out[(long)(gm + i) * HW + gn] = f2bf(acc[f][g][i]);
            }
    } else {
        float* Out = (float*)Outv + (long)b * oBatchStride;
#pragma unroll
        for (int f = 0; f < 4; ++f)
#pragma unroll
            for (int g = 0; g < 2; ++g) {
                const int gm = m0 + f * 16 + rq * 4;
                const int gn = n0 + wave * 32 + g * 16 + cl;
#pragma unroll
                for (int i = 0; i < 4; ++i)
                    Out[(long)(gm + i) * HW + gn] = acc[f][g][i];
            }
    }
}

// ---------------------------------------------------------------------------
// Depthwise 3x3 conv (SAME, zero pad), bf16 in/out, fp32 math.
// Also accumulates per-channel sum-of-squares for q/k channels (ch < 384).
// ---------------------------------------------------------------------------
__global__ __launch_bounds__(256) void dwconv_kernel(
    const unsigned short* __restrict__ qkv,
    const float* __restrict__ wdw,
    unsigned short* __restrict__ dwout,
    float* __restrict__ ssq)
{
    const int ht = blockIdx.x;   // 0..23 (8-row tiles)
    const int ch = blockIdx.y;   // 0..575
    const int b  = blockIdx.z;
    const int tid = threadIdx.x;
    const int h0 = ht * 8;

    __shared__ float s[10 * 194];
    __shared__ float wsm[9];
    __shared__ float red[4];

    if (tid < 9) wsm[tid] = wdw[ch * 9 + tid];
    if (tid < 20) { int r = tid >> 1; int c = (tid & 1) ? 193 : 0; s[r * 194 + c] = 0.f; }

    const long chbase = (long)(b * 576 + ch) * HW;
    for (int idx = tid; idx < 1920; idx += 256) {
        int r = idx / 192, w = idx - r * 192;
        int hh = h0 - 1 + r;
        float v = 0.f;
        if (hh >= 0 && hh < 192) v = bf2f(qkv[chbase + hh * 192 + w]);
        s[r * 194 + 1 + w] = v;
    }
    __syncthreads();

    const float w00 = wsm[0], w01 = wsm[1], w02 = wsm[2];
    const float w10 = wsm[3], w11 = wsm[4], w12 = wsm[5];
    const float w20 = wsm[6], w21 = wsm[7], w22 = wsm[8];

    float mysq = 0.f;
    for (int idx = tid; idx < 1536; idx += 256) {
        int hh = idx / 192, w = idx - hh * 192;
        const float* r0 = &s[hh * 194 + w];
        const float* r1 = r0 + 194;
        const float* r2 = r1 + 194;
        float acc = w00 * r0[0] + w01 * r0[1] + w02 * r0[2]
                  + w10 * r1[0] + w11 * r1[1] + w12 * r1[2]
                  + w20 * r2[0] + w21 * r2[1] + w22 * r2[2];
        dwout[chbase + (h0 + hh) * 192 + w] = f2bf(acc);
        mysq += acc * acc;
    }

    if (ch < 384) {
#pragma unroll
        for (int off = 32; off > 0; off >>= 1) mysq += __shfl_xor(mysq, off, 64);
        if ((tid & 63) == 0) red[tid >> 6] = mysq;
        __syncthreads();
        if (tid == 0) atomicAdd(&ssq[b * 384 + ch], red[0] + red[1] + red[2] + red[3]);
    }
}

// ---------------------------------------------------------------------------
// Gram: gram[b,h,d,e] += sum_n q[d][n]*k[e][n] over a 256-col chunk. MFMA TN.
// ---------------------------------------------------------------------------
__global__ __launch_bounds__(64) void gram_kernel(
    const unsigned short* __restrict__ dwb, float* __restrict__ gram)
{
    const int chunk = blockIdx.x;  // 0..143
    const int bh = blockIdx.y;     // 0..7
    const int b = bh >> 2, h = bh & 3;
    const int lane = threadIdx.x;
    const int row = lane & 15, qk = lane >> 4;
    const long n0 = (long)chunk * 256;

    const unsigned short* qb = dwb + (long)(b * 576 + h * 48) * HW + n0;
    const unsigned short* kb = dwb + (long)(b * 576 + 192 + h * 48) * HW + n0;

    f32x4 acc[3][3];
#pragma unroll
    for (int f = 0; f < 3; ++f)
#pragma unroll
        for (int g = 0; g < 3; ++g) acc[f][g] = (f32x4){0.f, 0.f, 0.f, 0.f};

    for (int kk = 0; kk < 256; kk += 32) {
        const int col = kk + qk * 8;
        bf16x8 aq[3], bk[3];
#pragma unroll
        for (int f = 0; f < 3; ++f) aq[f] = *(const bf16x8*)(qb + (long)(f * 16 + row) * HW + col);
#pragma unroll
        for (int g = 0; g < 3; ++g) bk[g] = *(const bf16x8*)(kb + (long)(g * 16 + row) * HW + col);
#pragma unroll
        for (int f = 0; f < 3; ++f)
#pragma unroll
            for (int g = 0; g < 3; ++g)
                acc[f][g] = __builtin_amdgcn_mfma_f32_16x16x32_bf16(aq[f], bk[g], acc[f][g], 0, 0, 0);
    }

    float* gb = gram + bh * 2304;
#pragma unroll
    for (int f = 0; f < 3; ++f)
#pragma unroll
        for (int g = 0; g < 3; ++g)
#pragma unroll
            for (int i = 0; i < 4; ++i)
                atomicAdd(&gb[(f * 16 + qk * 4 + i) * 48 + g * 16 + row], acc[f][g][i]);
}

// ---------------------------------------------------------------------------
// attn = softmax( gram / (|q_d||k_e|) * softplus(logT) + eps ) over e
// ---------------------------------------------------------------------------
__global__ __launch_bounds__(64) void attn_kernel(
    const float* __restrict__ gram, const float* __restrict__ ssq,
    const float* __restrict__ lt, float* __restrict__ attn)
{
    const int bh = blockIdx.x;
    const int b = bh >> 2, h = bh & 3;
    const int d = threadIdx.x;
    if (d >= 48) return;
    const float temp = log1pf(expf(lt[h])) + 1e-6f;
    const float invq = 1.f / fmaxf(sqrtf(ssq[b * 384 + h * 48 + d]), 1e-12f);
    float p[48];
    float mx = -1e30f;
#pragma unroll
    for (int e = 0; e < 48; ++e) {
        float invk = 1.f / fmaxf(sqrtf(ssq[b * 384 + 192 + h * 48 + e]), 1e-12f);
        float g = gram[bh * 2304 + d * 48 + e] * invq * invk * temp;
        p[e] = g;
        mx = fmaxf(mx, g);
    }
    float sum = 0.f;
#pragma unroll
    for (int e = 0; e < 48; ++e) { float x = expf(p[e] - mx); p[e] = x; sum += x; }
    const float inv = 1.f / sum;
#pragma unroll
    for (int e = 0; e < 48; ++e) attn[bh * 2304 + d * 48 + e] = p[e] * inv;
}

// ---------------------------------------------------------------------------
// M[b][o][h*48+e] = sum_d wproj[o][h*48+d] * attn[b][h][d][e]   (bf16 out)
// ---------------------------------------------------------------------------
__global__ __launch_bounds__(192) void mproj_kernel(
    const float* __restrict__ wproj, const float* __restrict__ attn,
    unsigned short* __restrict__ Mb)
{
    const int o = blockIdx.x;
    const int b = blockIdx.y;
    const int he = threadIdx.x;
    const int h = he / 48, e = he - h * 48;
    const float* ar = attn + ((b * 4 + h) * 48) * 48 + e;
    const float* wr = wproj + o * 192 + h * 48;
    float acc = 0.f;
#pragma unroll
    for (int d = 0; d < 48; ++d) acc += wr[d] * ar[d * 48];
    Mb[(long)(b * 192 + o) * 192 + he] = f2bf(acc);
}

__global__ void cvt_bf16_kernel(const float* __restrict__ in,
                                unsigned short* __restrict__ out, int n)
{
    int i = blockIdx.x * 256 + threadIdx.x;
    if (i < n) out[i] = f2bf(in[i]);
}

// ---------------------------------------------------------------------------
extern "C" void kernel_launch(void* const* d_in, const int* in_sizes, int n_in,
                              void* d_out, int out_size, void* d_ws, size_t ws_size,
                              hipStream_t stream)
{
    const float* x      = (const float*)d_in[0];
    const float* w_qkv  = (const float*)d_in[1];
    const float* w_dw   = (const float*)d_in[2];
    const float* w_proj = (const float*)d_in[3];
    const float* lt     = (const float*)d_in[4];

    char* ws = (char*)d_ws;
    unsigned short* wqkv_b = (unsigned short*)(ws + 0);          // 221184 B
    float* gram            = (float*)(ws + 221184);              // 73728 B
    float* ssq             = (float*)(ws + 294912);              // 3072 B
    float* attn            = (float*)(ws + 297984);              // 73728 B
    unsigned short* Mb     = (unsigned short*)(ws + 371712);     // 147456 B
    unsigned short* qkvb   = (unsigned short*)(ws + 524288);     // 84934656 B
    unsigned short* dwb    = (unsigned short*)(ws + 524288 + 84934656ll);

    // zero the atomic accumulators (gram + ssq are adjacent)
    hipMemsetAsync(gram, 0, 73728 + 3072, stream);

    // w_qkv -> bf16
    cvt_bf16_kernel<<<dim3((110592 + 255) / 256), 256, 0, stream>>>(w_qkv, wqkv_b, 110592);

    // qkv = w_qkv @ x   (M=576, K=192, N=HW per batch)
    gemm_bf16<true, true><<<dim3(9, 288, 2), 256, 0, stream>>>(
        wqkv_b, (const void*)x, (void*)qkvb,
        0L, (long)192 * HW, (long)576 * HW);

    // depthwise 3x3 + sumsq(q,k)
    dwconv_kernel<<<dim3(24, 576, 2), 256, 0, stream>>>(qkvb, w_dw, dwb, ssq);

    // gram = q @ k^T per (b, head)
    gram_kernel<<<dim3(144, 8), 64, 0, stream>>>(dwb, gram);

    // softmax(normalized gram * temperature)
    attn_kernel<<<dim3(8), 64, 0, stream>>>(gram, ssq, lt, attn);

    // M = w_proj @ attn (per batch, per head), bf16
    mproj_kernel<<<dim3(192, 2), 192, 0, stream>>>(w_proj, attn, Mb);

    // out = M @ v   (M=192, K=192, N=HW per batch), fp32 out
    gemm_bf16<false, false><<<dim3(3, 288, 2), 256, 0, stream>>>(
        Mb, (const void*)(dwb + (long)384 * HW), d_out,
        (long)192 * 192, (long)576 * HW, (long)192 * HW);
}